// Round 1
// baseline (276.641 us; speedup 1.0000x reference)
//
#include <hip/hip_runtime.h>
#include <cstdint>

typedef unsigned long long u64;

#define HW    12544      // 112*112
#define NCH   64
#define NBATCH 32
#define NPIX  401408     // 32*12544

// ---------------------------------------------------------------------------
// k_pack: blocks [0,1568): pack sign bits of x across channels into u64/pixel.
//         block 1568: pack W sign bits (9 taps x 64 cout masks over cin) + alpha.
// ---------------------------------------------------------------------------
__global__ __launch_bounds__(256) void k_pack(const float* __restrict__ x,
                                              const float* __restrict__ Wt,
                                              u64* __restrict__ xbits,
                                              u64* __restrict__ wbits,
                                              float* __restrict__ alpha) {
  int b = blockIdx.x;
  int t = threadIdx.x;
  if (b < 1568) {
    int n = b / 49;
    int p = (b % 49) * 256 + t;          // 49*256 = 12544 exactly
    const float* xp = x + (size_t)n * NCH * HW + p;
    u64 m = 0;
#pragma unroll 16
    for (int c = 0; c < 64; ++c) {
      m |= (u64)(xp[(size_t)c * HW] > 0.0f) << c;   // coalesced per iteration
    }
    xbits[(size_t)n * HW + p] = m;
  } else {
    // one block: 4 waves, wave wv packs couts [wv*16, wv*16+16)
    int wv = t >> 6, lane = t & 63;      // lane = cin
    for (int i = 0; i < 16; ++i) {
      int co = wv * 16 + i;
      const float* wp = Wt + ((size_t)co * 64 + lane) * 9;  // OIHW: [co][cin][kh][kw]
      float w9[9];
      float s = 0.0f;
#pragma unroll
      for (int k = 0; k < 9; ++k) { w9[k] = wp[k]; s += fabsf(w9[k]); }
#pragma unroll
      for (int off = 32; off > 0; off >>= 1) s += __shfl_xor(s, off);
#pragma unroll
      for (int k = 0; k < 9; ++k) {
        u64 msk = __ballot(w9[k] > 0.0f);  // bit cin = sign(+) of W[co][cin][tap k]
        if (lane == 0) wbits[k * 64 + co] = msk;
      }
      if (lane == 0) alpha[co] = s * (1.0f / 576.0f);
    }
  }
}

// ---------------------------------------------------------------------------
// k_stats: exact integer conv sums per output channel: S1 = sum I, S2 = sum I^2.
// Tile: one n, 2 rows (224 px). thread t -> cout = t&63, wave handles 56 px.
// ---------------------------------------------------------------------------
__global__ __launch_bounds__(256) void k_stats(const u64* __restrict__ xbits,
                                               const u64* __restrict__ wbits,
                                               u64* __restrict__ S1,
                                               u64* __restrict__ S2) {
  __shared__ u64 stg[4][114];     // rows h0-1..h0+2, cols -1..112, zero-padded halo
  __shared__ int corr[9][64];     // edge-type x cout correction
  __shared__ int red1[256];
  __shared__ int red2[256];
  int b = blockIdx.x, t = threadIdx.x;
  int n = b / 56, h0 = (b % 56) * 2;

  for (int i = t; i < 4 * 114; i += 256) {
    int r = i / 114, cc = i % 114;
    int h = h0 - 1 + r, w = cc - 1;
    u64 v = 0;
    if (h >= 0 && h < 112 && (unsigned)w < 112u)
      v = xbits[(size_t)n * HW + h * 112 + w];
    stg[r][cc] = v;
  }

  int c = t & 63, wv = t >> 6;
  u64 wm[9];
#pragma unroll
  for (int k = 0; k < 9; ++k) wm[k] = wbits[k * 64 + c];   // hoisted: c fixed per thread

  if (t < 64) {
    int pw[9];
#pragma unroll
    for (int k = 0; k < 9; ++k) pw[k] = __popcll(wm[k]);
#pragma unroll
    for (int ht = 0; ht < 3; ++ht)
#pragma unroll
      for (int wt = 0; wt < 3; ++wt) {
        int s = 0;
#pragma unroll
        for (int k = 0; k < 9; ++k) {
          int dh = k / 3 - 1, dw = k % 3 - 1;
          bool inval = (ht == 0 && dh < 0) || (ht == 2 && dh > 0) ||
                       (wt == 0 && dw < 0) || (wt == 2 && dw > 0);
          if (inval) s += 64 - 2 * pw[k];
        }
        corr[ht * 3 + wt][t] = s;
      }
  }
  __syncthreads();

  int s1 = 0, s2 = 0;
  for (int k = 0; k < 56; ++k) {
    int pl = wv * 56 + k;            // wave-uniform pixel
    int hl = pl / 112, w = pl % 112;
    int h = h0 + hl;
    int ht = (h == 0) ? 0 : ((h == 111) ? 2 : 1);
    int wt = (w == 0) ? 0 : ((w == 111) ? 2 : 1);
    int sum = 0;
#pragma unroll
    for (int kk = 0; kk < 9; ++kk)
      sum += __popcll(stg[hl + kk / 3][w + kk % 3] ^ wm[kk]);  // stg: LDS broadcast
    int I = 576 - 2 * sum - corr[ht * 3 + wt][c];
    s1 += I;
    s2 += I * I;                     // max 56*576^2 = 18.6M, fits int32
  }
  red1[t] = s1; red2[t] = s2;
  __syncthreads();
  if (t < 64) {
    int a1 = red1[t] + red1[t + 64] + red1[t + 128] + red1[t + 192];
    int a2 = red2[t] + red2[t + 64] + red2[t + 128] + red2[t + 192];
    atomicAdd(&S1[t], (u64)(long long)a1);   // two's complement wrap = exact int64 sum
    atomicAdd(&S2[t], (u64)(long long)a2);
  }
}

// ---------------------------------------------------------------------------
// k_final: recompute conv from bits, apply alpha/BN/hardtanh/residual, store.
// Tile: one n, 2 rows; thread t<224 -> one pixel, loops all 64 couts (coalesced IO).
// ---------------------------------------------------------------------------
__global__ __launch_bounds__(256) void k_final(const float* __restrict__ x,
                                               const u64* __restrict__ xbits,
                                               const u64* __restrict__ wbits,
                                               const u64* __restrict__ S1,
                                               const u64* __restrict__ S2,
                                               const float* __restrict__ alpha,
                                               const float* __restrict__ gamma,
                                               const float* __restrict__ beta,
                                               float* __restrict__ out) {
  __shared__ u64 stg[4][114];
  __shared__ u64 wsh[576];
  __shared__ int corr[9][64];
  __shared__ float scs[64];
  __shared__ float bis[64];
  int b = blockIdx.x, t = threadIdx.x;
  int n = b / 56, h0 = (b % 56) * 2;

  for (int i = t; i < 4 * 114; i += 256) {
    int r = i / 114, cc = i % 114;
    int h = h0 - 1 + r, w = cc - 1;
    u64 v = 0;
    if (h >= 0 && h < 112 && (unsigned)w < 112u)
      v = xbits[(size_t)n * HW + h * 112 + w];
    stg[r][cc] = v;
  }
  for (int i = t; i < 576; i += 256) wsh[i] = wbits[i];

  if (t < 64) {
    int pw[9];
#pragma unroll
    for (int k = 0; k < 9; ++k) pw[k] = __popcll(wbits[k * 64 + t]);
#pragma unroll
    for (int ht = 0; ht < 3; ++ht)
#pragma unroll
      for (int wt = 0; wt < 3; ++wt) {
        int s = 0;
#pragma unroll
        for (int k = 0; k < 9; ++k) {
          int dh = k / 3 - 1, dw = k % 3 - 1;
          bool inval = (ht == 0 && dh < 0) || (ht == 2 && dh > 0) ||
                       (wt == 0 && dw < 0) || (wt == 2 && dw > 0);
          if (inval) s += 64 - 2 * pw[k];
        }
        corr[ht * 3 + wt][t] = s;
      }
    // fold BN-prep: scale/bias per channel from exact integer stats
    long long s1 = (long long)S1[t];
    long long s2 = (long long)S2[t];
    double inv = 1.0 / (double)NPIX;
    double mean = (double)s1 * inv;                 // mean of integer conv I
    double var = (double)s2 * inv - mean * mean;    // biased var of I
    double al = (double)alpha[t];
    double rs = 1.0 / sqrt(al * al * var + 1e-5);
    double sc = (double)gamma[t] * al * rs;
    scs[t] = (float)sc;
    bis[t] = (float)((double)beta[t] - sc * mean);
  }
  __syncthreads();

  if (t < 224) {
    int hl = t / 112, w = t % 112;
    int h = h0 + hl;
    int ht = (h == 0) ? 0 : ((h == 111) ? 2 : 1);
    int wt = (w == 0) ? 0 : ((w == 111) ? 2 : 1);
    int type = ht * 3 + wt;
    u64 xm[9];
#pragma unroll
    for (int kk = 0; kk < 9; ++kk) xm[kk] = stg[hl + kk / 3][w + kk % 3];
    const float* xp = x + (size_t)n * NCH * HW + (size_t)h * 112 + w;
    float* op = out + (size_t)n * NCH * HW + (size_t)h * 112 + w;
#pragma unroll 4
    for (int c = 0; c < 64; ++c) {
      int sum = 0;
#pragma unroll
      for (int kk = 0; kk < 9; ++kk) sum += __popcll(xm[kk] ^ wsh[kk * 64 + c]);
      int I = 576 - 2 * sum - corr[type][c];
      float o = fmaf((float)I, scs[c], bis[c]);
      o = fminf(fmaxf(o, -1.0f), 1.0f);
      op[(size_t)c * HW] = o + xp[(size_t)c * HW];
    }
  }
}

// ---------------------------------------------------------------------------
extern "C" void kernel_launch(void* const* d_in, const int* in_sizes, int n_in,
                              void* d_out, int out_size, void* d_ws, size_t ws_size,
                              hipStream_t stream) {
  const float* x     = (const float*)d_in[0];
  const float* W     = (const float*)d_in[1];
  const float* gamma = (const float*)d_in[2];
  const float* beta  = (const float*)d_in[3];
  float* out = (float*)d_out;

  char* ws = (char*)d_ws;
  u64*  S1    = (u64*)(ws + 0);        // 64 * 8 B
  u64*  S2    = (u64*)(ws + 512);      // 64 * 8 B
  float* alpha = (float*)(ws + 1024);  // 64 * 4 B
  u64*  wbits = (u64*)(ws + 2048);     // 576 * 8 B
  u64*  xbits = (u64*)(ws + 8192);     // 401408 * 8 B = 3.2 MB

  hipMemsetAsync(ws, 0, 1024, stream);  // zero S1/S2 (ws is poisoned 0xAA each run)

  hipLaunchKernelGGL(k_pack, dim3(1569), dim3(256), 0, stream, x, W, xbits, wbits, alpha);
  hipLaunchKernelGGL(k_stats, dim3(32 * 56), dim3(256), 0, stream, xbits, wbits, S1, S2);
  hipLaunchKernelGGL(k_final, dim3(32 * 56), dim3(256), 0, stream,
                     x, xbits, wbits, S1, S2, alpha, gamma, beta, out);
}

// Round 3
// 266.804 us; speedup vs baseline: 1.0369x; 1.0369x over previous
//
#include <hip/hip_runtime.h>
#include <cstdint>

typedef unsigned long long u64;

#define HW    12544      // 112*112
#define NPIX  401408     // 32*12544

// ---------------------------------------------------------------------------
// k_pack: blocks [0,392): pack sign bits of x, 4 pixels per thread via float4.
//         block 392: pack W sign bits + alpha, and zero S1/S2 (first 128 u64 of ws).
// ---------------------------------------------------------------------------
__global__ __launch_bounds__(256) void k_pack(const float* __restrict__ x,
                                              const float* __restrict__ Wt,
                                              u64* __restrict__ xbits,
                                              u64* __restrict__ wbits,
                                              float* __restrict__ alpha,
                                              u64* __restrict__ stats) {
  int b = blockIdx.x;
  int t = threadIdx.x;
  if (b < 392) {
    int gp = (b * 256 + t) * 4;          // 392*256*4 = 401408 = NPIX exactly
    int n = gp / HW, p = gp % HW;        // HW%4==0 -> float4 never crosses n
    const float* xp = x + (size_t)n * 64 * HW + p;
    u64 m0 = 0, m1 = 0, m2 = 0, m3 = 0;
#pragma unroll 8
    for (int c = 0; c < 64; ++c) {
      const float4 v = *reinterpret_cast<const float4*>(xp + (size_t)c * HW);
      m0 |= (u64)(v.x > 0.0f) << c;
      m1 |= (u64)(v.y > 0.0f) << c;
      m2 |= (u64)(v.z > 0.0f) << c;
      m3 |= (u64)(v.w > 0.0f) << c;
    }
    ulonglong2* d2 = reinterpret_cast<ulonglong2*>(xbits + (size_t)n * HW + p);
    d2[0] = make_ulonglong2(m0, m1);
    d2[1] = make_ulonglong2(m2, m3);
  } else {
    if (t < 128) stats[t] = 0;           // zero S1[64] + S2[64] (replaces memset)
    int wv = t >> 6, lane = t & 63;      // lane = cin
    for (int i = 0; i < 16; ++i) {
      int co = wv * 16 + i;
      const float* wp = Wt + ((size_t)co * 64 + lane) * 9;  // OIHW
      float w9[9];
      float s = 0.0f;
#pragma unroll
      for (int k = 0; k < 9; ++k) { w9[k] = wp[k]; s += fabsf(w9[k]); }
#pragma unroll
      for (int off = 32; off > 0; off >>= 1) s += __shfl_xor(s, off);
#pragma unroll
      for (int k = 0; k < 9; ++k) {
        u64 msk = __ballot(w9[k] > 0.0f);
        if (lane == 0) wbits[k * 64 + co] = msk;
      }
      if (lane == 0) alpha[co] = s * (1.0f / 576.0f);
    }
  }
}

// ---------------------------------------------------------------------------
// k_stats: exact integer conv sums S1=sum I, S2=sum I^2 per output channel.
// Tile: one n, 8 rows. thread t -> cout=t&63; wave wv walks 56 strip-columns,
// each strip = 4 vertical pixels (18 broadcast LDS reads serve 4 windows).
// ---------------------------------------------------------------------------
__global__ __launch_bounds__(256) void k_stats(const u64* __restrict__ xbits,
                                               const u64* __restrict__ wbits,
                                               u64* __restrict__ S1,
                                               u64* __restrict__ S2) {
  __shared__ u64 stg[10][114];   // rows h0-1..h0+8, cols -1..112, zero halo
  __shared__ int red1[256];
  __shared__ int red2[256];
  int b = blockIdx.x, t = threadIdx.x;
  int n = b / 14, h0 = (b % 14) * 8;

  for (int i = t; i < 10 * 114; i += 256) {
    int r = i / 114, cc = i % 114;
    int h = h0 - 1 + r, w = cc - 1;
    u64 v = 0;
    if ((unsigned)h < 112u && (unsigned)w < 112u)
      v = xbits[(size_t)n * HW + h * 112 + w];
    stg[r][cc] = v;
  }

  int c = t & 63, wv = t >> 6;
  u64 wm0, wm1, wm2, wm3, wm4, wm5, wm6, wm7, wm8;
  wm0 = wbits[0 * 64 + c]; wm1 = wbits[1 * 64 + c]; wm2 = wbits[2 * 64 + c];
  wm3 = wbits[3 * 64 + c]; wm4 = wbits[4 * 64 + c]; wm5 = wbits[5 * 64 + c];
  wm6 = wbits[6 * 64 + c]; wm7 = wbits[7 * 64 + c]; wm8 = wbits[8 * 64 + c];
  int pw0 = __popcll(wm0), pw1 = __popcll(wm1), pw2 = __popcll(wm2);
  int pw3 = __popcll(wm3), pw4 = __popcll(wm4), pw5 = __popcll(wm5);
  int pw6 = __popcll(wm6), pw7 = __popcll(wm7), pw8 = __popcll(wm8);
  // padding corrections (64-2*pw = sum over cin of sign(w) for a zero-padded tap)
  int vtop = (64-2*pw0) + (64-2*pw1) + (64-2*pw2);
  int vbot = (64-2*pw6) + (64-2*pw7) + (64-2*pw8);
  int hlft = (64-2*pw0) + (64-2*pw3) + (64-2*pw6);
  int hrgt = (64-2*pw2) + (64-2*pw5) + (64-2*pw8);
  int cTL = 64-2*pw0, cTR = 64-2*pw2, cBL = 64-2*pw6, cBR = 64-2*pw8;
  __syncthreads();

  int s1 = 0, s2 = 0;
  for (int it = 0; it < 56; ++it) {
    int idx = wv * 56 + it;              // wave-uniform
    int s = idx / 112, w = idx % 112;
    int r0 = s * 4;
    u64 a0 = stg[r0+0][w], a1 = stg[r0+0][w+1], a2 = stg[r0+0][w+2];
    u64 b0 = stg[r0+1][w], b1 = stg[r0+1][w+1], b2 = stg[r0+1][w+2];
    u64 c0 = stg[r0+2][w], c1 = stg[r0+2][w+1], c2 = stg[r0+2][w+2];
    u64 d0 = stg[r0+3][w], d1 = stg[r0+3][w+1], d2 = stg[r0+3][w+2];
    u64 e0 = stg[r0+4][w], e1 = stg[r0+4][w+1], e2 = stg[r0+4][w+2];
    u64 f0 = stg[r0+5][w], f1 = stg[r0+5][w+1], f2 = stg[r0+5][w+2];
    int wl = (w == 0), wr = (w == 111);
    int hcor = wl ? hlft : (wr ? hrgt : 0);
    int ctop = hcor, cbot = hcor;
    if (h0 + s * 4 == 0)        ctop += vtop - (wl ? cTL : 0) - (wr ? cTR : 0);
    if (h0 + s * 4 + 3 == 111)  cbot += vbot - (wl ? cBL : 0) - (wr ? cBR : 0);
#define PX(x0,x1,x2,x3,x4,x5,x6,x7,x8,corr)                                    \
    { int sum = __popcll((x0)^wm0)+__popcll((x1)^wm1)+__popcll((x2)^wm2)       \
              + __popcll((x3)^wm3)+__popcll((x4)^wm4)+__popcll((x5)^wm5)       \
              + __popcll((x6)^wm6)+__popcll((x7)^wm7)+__popcll((x8)^wm8);      \
      int I = 576 - 2*sum - (corr); s1 += I; s2 += I*I; }
    PX(a0,a1,a2,b0,b1,b2,c0,c1,c2, ctop);
    PX(b0,b1,b2,c0,c1,c2,d0,d1,d2, hcor);
    PX(c0,c1,c2,d0,d1,d2,e0,e1,e2, hcor);
    PX(d0,d1,d2,e0,e1,e2,f0,f1,f2, cbot);
#undef PX
  }
  red1[t] = s1; red2[t] = s2;
  __syncthreads();
  if (t < 64) {
    int a1s = red1[t] + red1[t+64] + red1[t+128] + red1[t+192];
    int a2s = red2[t] + red2[t+64] + red2[t+128] + red2[t+192];
    atomicAdd(&S1[t], (u64)(long long)a1s);
    atomicAdd(&S2[t], (u64)(long long)a2s);
  }
}

// ---------------------------------------------------------------------------
// k_final: recompute conv, apply alpha/BN/hardtanh/residual.
// Tile: one n, 8 rows. thread t<224 -> (w = t%112, strip s = t/112): a vertical
// strip of 4 pixels; 18 mask regs serve 4 windows; per-c LDS reads amortized 4x.
// ---------------------------------------------------------------------------
__global__ __launch_bounds__(256) void k_final(const float* __restrict__ x,
                                               const u64* __restrict__ xbits,
                                               const u64* __restrict__ wbits,
                                               const u64* __restrict__ S1,
                                               const u64* __restrict__ S2,
                                               const float* __restrict__ alpha,
                                               const float* __restrict__ gamma,
                                               const float* __restrict__ beta,
                                               float* __restrict__ out) {
  __shared__ u64 stg[10][114];
  __shared__ u64 wsh[576];
  __shared__ int corrs[9 * 64];
  __shared__ float scs[64];
  __shared__ float bis[64];
  int b = blockIdx.x, t = threadIdx.x;
  int n = b / 14, h0 = (b % 14) * 8;

  for (int i = t; i < 10 * 114; i += 256) {
    int r = i / 114, cc = i % 114;
    int h = h0 - 1 + r, w = cc - 1;
    u64 v = 0;
    if ((unsigned)h < 112u && (unsigned)w < 112u)
      v = xbits[(size_t)n * HW + h * 112 + w];
    stg[r][cc] = v;
  }
  for (int i = t; i < 576; i += 256) wsh[i] = wbits[i];

  if (t < 64) {
    int pw[9];
#pragma unroll
    for (int k = 0; k < 9; ++k) pw[k] = __popcll(wbits[k * 64 + t]);
#pragma unroll
    for (int ht = 0; ht < 3; ++ht)
#pragma unroll
      for (int wt = 0; wt < 3; ++wt) {
        int s = 0;
#pragma unroll
        for (int k = 0; k < 9; ++k) {
          int dh = k / 3 - 1, dw = k % 3 - 1;
          bool inval = (ht == 0 && dh < 0) || (ht == 2 && dh > 0) ||
                       (wt == 0 && dw < 0) || (wt == 2 && dw > 0);
          if (inval) s += 64 - 2 * pw[k];
        }
        corrs[(ht * 3 + wt) * 64 + t] = s;
      }
    long long s1 = (long long)S1[t];
    long long s2 = (long long)S2[t];
    double inv = 1.0 / (double)NPIX;
    double mean = (double)s1 * inv;
    double var = (double)s2 * inv - mean * mean;
    double al = (double)alpha[t];
    double rs = 1.0 / sqrt(al * al * var + 1e-5);
    double sc = (double)gamma[t] * al * rs;
    scs[t] = (float)sc;
    bis[t] = (float)((double)beta[t] - sc * mean);
  }
  __syncthreads();

  if (t < 224) {
    int w = t % 112, s = t / 112;
    int r0 = s * 4;
    int hb = h0 + s * 4;                 // image row of strip's first pixel
    u64 a0 = stg[r0+0][w], a1 = stg[r0+0][w+1], a2 = stg[r0+0][w+2];
    u64 b0 = stg[r0+1][w], b1 = stg[r0+1][w+1], b2 = stg[r0+1][w+2];
    u64 c0 = stg[r0+2][w], c1 = stg[r0+2][w+1], c2 = stg[r0+2][w+2];
    u64 d0 = stg[r0+3][w], d1 = stg[r0+3][w+1], d2 = stg[r0+3][w+2];
    u64 e0 = stg[r0+4][w], e1 = stg[r0+4][w+1], e2 = stg[r0+4][w+2];
    u64 f0 = stg[r0+5][w], f1 = stg[r0+5][w+1], f2 = stg[r0+5][w+2];
    int wl = (w == 0), wr = (w == 111);
    int wt = wl ? 0 : (wr ? 2 : 1);
    int ttop = ((hb == 0) ? 0 : 1) * 3 + wt;        // row r=0 edge type
    int tmid = 3 + wt;
    int tbot = ((hb + 3 == 111) ? 2 : 1) * 3 + wt;  // row r=3 edge type
    const float* xp = x + (size_t)n * 64 * HW + (size_t)hb * 112 + w;
    float* op = out + (size_t)n * 64 * HW + (size_t)hb * 112 + w;
#pragma unroll 2
    for (int c = 0; c < 64; ++c) {
      int off = c * HW;                  // < 2^20 elements, int is fine
      float x0 = xp[off], x1 = xp[off + 112], x2 = xp[off + 224], x3 = xp[off + 336];
      u64 w0 = wsh[c],       w1 = wsh[64 + c],  w2 = wsh[128 + c];
      u64 w3 = wsh[192 + c], w4 = wsh[256 + c], w5 = wsh[320 + c];
      u64 w6 = wsh[384 + c], w7 = wsh[448 + c], w8 = wsh[512 + c];
      float sc = scs[c], bi = bis[c];
      int ct = corrs[ttop * 64 + c];
      int cm = corrs[tmid * 64 + c];
      int cb = corrs[tbot * 64 + c];
#define SUM9(x0_,x1_,x2_,x3_,x4_,x5_,x6_,x7_,x8_)                              \
      (__popcll((x0_)^w0)+__popcll((x1_)^w1)+__popcll((x2_)^w2)                \
      +__popcll((x3_)^w3)+__popcll((x4_)^w4)+__popcll((x5_)^w5)                \
      +__popcll((x6_)^w6)+__popcll((x7_)^w7)+__popcll((x8_)^w8))
      int I0 = 576 - 2 * SUM9(a0,a1,a2,b0,b1,b2,c0,c1,c2) - ct;
      int I1 = 576 - 2 * SUM9(b0,b1,b2,c0,c1,c2,d0,d1,d2) - cm;
      int I2 = 576 - 2 * SUM9(c0,c1,c2,d0,d1,d2,e0,e1,e2) - cm;
      int I3 = 576 - 2 * SUM9(d0,d1,d2,e0,e1,e2,f0,f1,f2) - cb;
#undef SUM9
      float o0 = fminf(fmaxf(fmaf((float)I0, sc, bi), -1.0f), 1.0f);
      float o1 = fminf(fmaxf(fmaf((float)I1, sc, bi), -1.0f), 1.0f);
      float o2 = fminf(fmaxf(fmaf((float)I2, sc, bi), -1.0f), 1.0f);
      float o3 = fminf(fmaxf(fmaf((float)I3, sc, bi), -1.0f), 1.0f);
      op[off]       = o0 + x0;
      op[off + 112] = o1 + x1;
      op[off + 224] = o2 + x2;
      op[off + 336] = o3 + x3;
    }
  }
}

// ---------------------------------------------------------------------------
extern "C" void kernel_launch(void* const* d_in, const int* in_sizes, int n_in,
                              void* d_out, int out_size, void* d_ws, size_t ws_size,
                              hipStream_t stream) {
  const float* x     = (const float*)d_in[0];
  const float* W     = (const float*)d_in[1];
  const float* gamma = (const float*)d_in[2];
  const float* beta  = (const float*)d_in[3];
  float* out = (float*)d_out;

  char* ws = (char*)d_ws;
  u64*   S1    = (u64*)(ws + 0);        // 64 * 8 B
  u64*   S2    = (u64*)(ws + 512);      // 64 * 8 B
  float* alpha = (float*)(ws + 1024);   // 64 * 4 B
  u64*   wbits = (u64*)(ws + 2048);     // 576 * 8 B
  u64*   xbits = (u64*)(ws + 8192);     // 401408 * 8 B = 3.2 MB

  hipLaunchKernelGGL(k_pack, dim3(393), dim3(256), 0, stream,
                     x, W, xbits, wbits, alpha, (u64*)ws);
  hipLaunchKernelGGL(k_stats, dim3(32 * 14), dim3(256), 0, stream,
                     xbits, wbits, S1, S2);
  hipLaunchKernelGGL(k_final, dim3(32 * 14), dim3(256), 0, stream,
                     x, xbits, wbits, S1, S2, alpha, gamma, beta, out);
}